// Round 3
// baseline (48335.611 us; speedup 1.0000x reference)
//
#include <hip/hip_runtime.h>

#define T_LEN 8192
#define NIN   40
#define E_DIM 256
#define HID   512
#define G4H   2048
#define RD    8     // h2 ring depth (L1 waves provably within 1 step of each other)

// ---------- MALL-coherent (cross-XCD) access, inline asm ----------
__device__ __forceinline__ float4 ld4_sc(const float* p) {
  float4 v;
  asm volatile("global_load_dwordx4 %0, %1, off sc0 sc1" : "=v"(v) : "v"(p));
  return v;  // NOT valid until s_waitcnt vmcnt(0)
}
__device__ __forceinline__ void st2_sc(float* p, float h, unsigned seq) {
  union { float2 f; uint2 u; } pv;
  pv.u.x = __float_as_uint(h); pv.u.y = seq;
  asm volatile("global_store_dwordx2 %0, %1, off sc0 sc1" :: "v"(p), "v"(pv.f) : "memory");
}
#define VM_FENCE() do { asm volatile("s_waitcnt vmcnt(0)" ::: "memory"); \
                        __builtin_amdgcn_sched_barrier(0); } while (0)

__device__ __forceinline__ float sigm(float x) {
  x = fminf(20.f, fmaxf(-20.f, x));
  float e = __builtin_amdgcn_exp2f(-1.442695040888963f * x);
  return __builtin_amdgcn_rcpf(1.f + e);
}
__device__ __forceinline__ float tanh_f(float x) {
  x = fminf(10.f, fmaxf(-10.f, x));
  float e = __builtin_amdgcn_exp2f(-2.885390081777927f * x);  // e^(-2x)
  return (1.f - e) * __builtin_amdgcn_rcpf(1.f + e);
}
__device__ __forceinline__ float sel4(int k, float a0, float a1, float a2, float a3) {
  float r = a0;
  r = (k == 1) ? a1 : r;
  r = (k == 2) ? a2 : r;
  r = (k == 3) ? a3 : r;
  return r;
}

// ---------------- phase 0: W_comb = W_ih0 @ W_in  [2048 x 40], bias_comb ----
__global__ __launch_bounds__(64) void prep_kernel(
    const float* __restrict__ W_in, const float* __restrict__ b_in,
    const float* __restrict__ W_ih0, const float* __restrict__ b_ih0,
    const float* __restrict__ b_hh0,
    float* __restrict__ W_comb, float* __restrict__ bias_comb)
{
  const int r = blockIdx.x;        // 0..2047
  const int lane = threadIdx.x;    // 0..63
  float bp = 0.f;
  for (int e = lane; e < E_DIM; e += 64) bp += W_ih0[(size_t)r * E_DIM + e] * b_in[e];
  float acc = 0.f;
  if (lane < NIN) {
    for (int e = 0; e < E_DIM; ++e)
      acc += W_ih0[(size_t)r * E_DIM + e] * W_in[(size_t)e * NIN + lane];
  }
#pragma unroll
  for (int m = 1; m < 64; m <<= 1) bp += __shfl_xor(bp, m, 64);
  if (lane < NIN) W_comb[(size_t)r * NIN + lane] = acc;
  if (lane == 0) bias_comb[r] = bp + b_ih0[r] + b_hh0[r];
}

// ---------------- phase 1: barrier-free pipelined 2-layer scan ----------------
// 512 blocks x 64 threads (one wave each, fully independent; no __syncthreads,
// no flags). h exchanged as {f32,seq} 8B atomic pairs; consumers poll the data.
// blocks 0..255: layer0 unit pair bid*2. blocks 256..511: layer1 unit pair.
__global__ __launch_bounds__(64, 1) void scan_kernel(
    const float* __restrict__ in_states,
    const float* __restrict__ W_hh0,
    const float* __restrict__ W_ih1,
    const float* __restrict__ W_hh1,
    const float* __restrict__ b_ih1,
    const float* __restrict__ b_hh1,
    const float* __restrict__ W_comb,
    const float* __restrict__ bias_comb,
    const float* __restrict__ W_out,
    const float* __restrict__ b_out,
    float* __restrict__ h1pair,   // [T][512] pairs (full history)
    float* __restrict__ h2ring,   // [RD][512] pairs (ring)
    float* __restrict__ d_out)
{
  const int lane = threadIdx.x;      // 0..63
  const int bid  = blockIdx.x;
  const int G    = (lane & 2) | ((lane >> 2) & 1);   // gate id after collapse

  if (bid < 256) {
    // ======================= layer 0 (units uA, uA+1) =======================
    const int uA = bid * 2;
    float w[8][8];                   // W_hh0 rows q: gate=q&3, unit=q>>2
#pragma unroll
    for (int q = 0; q < 8; ++q) {
      int R = (q & 3) * HID + uA + (q >> 2);
      const float4* p = (const float4*)(W_hh0 + (size_t)R * HID + lane * 8);
      float4 a = p[0], b = p[1];
      w[q][0]=a.x; w[q][1]=a.y; w[q][2]=a.z; w[q][3]=a.w;
      w[q][4]=b.x; w[q][5]=b.y; w[q][6]=b.z; w[q][7]=b.w;
    }
    float w2[8];                     // W_comb col `lane` for the 8 rows
#pragma unroll
    for (int q = 0; q < 8; ++q) {
      int R = (q & 3) * HID + uA + (q >> 2);
      w2[q] = (lane < NIN) ? W_comb[(size_t)R * NIN + lane] : 0.f;
    }
    const float bias_lane = bias_comb[G * HID + uA + (lane & 1)];
    float in_cur = (lane < NIN) ? in_states[lane] : 0.f;
    float c_reg = 0.f;

    for (int t = 0; t < T_LEN; ++t) {
      float in_nxt = (lane < NIN && t + 1 < T_LEN)
                   ? in_states[(size_t)(t + 1) * NIN + lane] : 0.f;
      float hv[8];
      if (t > 0) {
        const float* hp = h1pair + ((size_t)(t - 1) << 10) + lane * 16;
        const unsigned e = (unsigned)t;  // stored seq = (t-1)+1
        float4 A, B, C, D; int ok;
        do {
          A = ld4_sc(hp); B = ld4_sc(hp + 4); C = ld4_sc(hp + 8); D = ld4_sc(hp + 12);
          VM_FENCE();
          unsigned bad = (__float_as_uint(A.y) ^ e) | (__float_as_uint(A.w) ^ e)
                       | (__float_as_uint(B.y) ^ e) | (__float_as_uint(B.w) ^ e)
                       | (__float_as_uint(C.y) ^ e) | (__float_as_uint(C.w) ^ e)
                       | (__float_as_uint(D.y) ^ e) | (__float_as_uint(D.w) ^ e);
          ok = (bad == 0u);
        } while (!__all(ok));
        hv[0]=A.x; hv[1]=A.z; hv[2]=B.x; hv[3]=B.z;
        hv[4]=C.x; hv[5]=C.z; hv[6]=D.x; hv[7]=D.z;
      } else {
#pragma unroll
        for (int j = 0; j < 8; ++j) hv[j] = 0.f;
      }
      float acc[8];
#pragma unroll
      for (int q = 0; q < 8; ++q) acc[q] = w2[q] * in_cur;   // input-dot share
#pragma unroll
      for (int cc = 0; cc < 8; ++cc) {
#pragma unroll
        for (int q = 0; q < 8; ++q) acc[q] = fmaf(w[q][cc], hv[cc], acc[q]);
      }
      // collapsing butterfly: 8 accs / 64 lanes -> 1 value per lane
      float a4[4];
#pragma unroll
      for (int g = 0; g < 4; ++g) {
        float send = (lane & 1) ? acc[g] : acc[g + 4];
        float recv = __shfl_xor(send, 1, 64);
        a4[g] = ((lane & 1) ? acc[g + 4] : acc[g]) + recv;
      }
      float b2[2];
#pragma unroll
      for (int j = 0; j < 2; ++j) {
        float send = (lane & 2) ? a4[j] : a4[j + 2];
        float recv = __shfl_xor(send, 2, 64);
        b2[j] = ((lane & 2) ? a4[j + 2] : a4[j]) + recv;
      }
      float c1;
      {
        float send = (lane & 4) ? b2[0] : b2[1];
        float recv = __shfl_xor(send, 4, 64);
        c1 = ((lane & 4) ? b2[1] : b2[0]) + recv;
      }
      c1 += __shfl_xor(c1, 8, 64);
      c1 += __shfl_xor(c1, 16, 64);
      c1 += __shfl_xor(c1, 32, 64);
      float pre = c1 + bias_lane;    // lane holds (unit uA+(lane&1), gate G)
      float s2 = __shfl_xor(pre, 2, 64);   // gate G^2
      float s4 = __shfl_xor(pre, 4, 64);   // gate G^1
      float s6 = __shfl_xor(pre, 6, 64);   // gate G^3
      float prei = sel4(G,     pre, s4, s2, s6);
      float pref = sel4(G ^ 1, pre, s4, s2, s6);
      float preg = sel4(G ^ 2, pre, s4, s2, s6);
      float preo = sel4(G ^ 3, pre, s4, s2, s6);
      float gi = sigm(prei), gf = sigm(pref), gg = tanh_f(preg), go = sigm(preo);
      c_reg = gf * c_reg + gi * gg;
      float hnew = go * tanh_f(c_reg);
      if (lane < 2) {
        st2_sc(h1pair + ((size_t)t << 10) + (uA + lane) * 2, hnew, (unsigned)(t + 1));
        if (t == T_LEN - 1) {
          d_out[T_LEN + uA + lane] = hnew;              // hT0
          d_out[T_LEN + 2 * HID + uA + lane] = c_reg;   // cT0
        }
      }
      in_cur = in_nxt;
    }
  } else {
    // ======================= layer 1 (units uB, uB+1) =======================
    const int uB = (bid - 256) * 2;
    const float* Wsrc = (lane < 32) ? W_ih1 : W_hh1;
    const int c0 = (lane & 31) * 16;
    float w[8][16];
#pragma unroll
    for (int q = 0; q < 8; ++q) {
      int R = (q & 3) * HID + uB + (q >> 2);
      const float4* p = (const float4*)(Wsrc + (size_t)R * HID + c0);
      float4 x0 = p[0], x1 = p[1], x2 = p[2], x3 = p[3];
      w[q][0]=x0.x;  w[q][1]=x0.y;  w[q][2]=x0.z;  w[q][3]=x0.w;
      w[q][4]=x1.x;  w[q][5]=x1.y;  w[q][6]=x1.z;  w[q][7]=x1.w;
      w[q][8]=x2.x;  w[q][9]=x2.y;  w[q][10]=x2.z; w[q][11]=x2.w;
      w[q][12]=x3.x; w[q][13]=x3.y; w[q][14]=x3.z; w[q][15]=x3.w;
    }
    const int brow = G * HID + uB + (lane & 1);
    const float bias_lane = b_ih1[brow] + b_hh1[brow];
    const float wout_lane = W_out[uB + (lane & 1)];
    const float b_out0 = b_out[0];
    float c_reg = 0.f;

    for (int t = 0; t < T_LEN; ++t) {
      const bool is_h1 = (lane < 32);
      const bool hvalid = is_h1 || (t > 0);
      const int rslot = (t > 0) ? ((t - 1) % RD) : 0;
      const float* hp = is_h1
          ? (h1pair + ((size_t)t << 10) + lane * 32)
          : (h2ring + (size_t)rslot * 1024 + (lane - 32) * 32);
      const unsigned e = is_h1 ? (unsigned)(t + 1) : (unsigned)t;
      float4 P0, P1, P2, P3, P4, P5, P6, P7; int ok;
      do {
        P0 = ld4_sc(hp);      P1 = ld4_sc(hp + 4);
        P2 = ld4_sc(hp + 8);  P3 = ld4_sc(hp + 12);
        P4 = ld4_sc(hp + 16); P5 = ld4_sc(hp + 20);
        P6 = ld4_sc(hp + 24); P7 = ld4_sc(hp + 28);
        VM_FENCE();
        unsigned bad = (__float_as_uint(P0.y) ^ e) | (__float_as_uint(P0.w) ^ e)
                     | (__float_as_uint(P1.y) ^ e) | (__float_as_uint(P1.w) ^ e)
                     | (__float_as_uint(P2.y) ^ e) | (__float_as_uint(P2.w) ^ e)
                     | (__float_as_uint(P3.y) ^ e) | (__float_as_uint(P3.w) ^ e)
                     | (__float_as_uint(P4.y) ^ e) | (__float_as_uint(P4.w) ^ e)
                     | (__float_as_uint(P5.y) ^ e) | (__float_as_uint(P5.w) ^ e)
                     | (__float_as_uint(P6.y) ^ e) | (__float_as_uint(P6.w) ^ e)
                     | (__float_as_uint(P7.y) ^ e) | (__float_as_uint(P7.w) ^ e);
        ok = (bad == 0u) || !hvalid;
      } while (!__all(ok));
      float hv[16];
      hv[0]=P0.x;  hv[1]=P0.z;  hv[2]=P1.x;  hv[3]=P1.z;
      hv[4]=P2.x;  hv[5]=P2.z;  hv[6]=P3.x;  hv[7]=P3.z;
      hv[8]=P4.x;  hv[9]=P4.z;  hv[10]=P5.x; hv[11]=P5.z;
      hv[12]=P6.x; hv[13]=P6.z; hv[14]=P7.x; hv[15]=P7.z;
      if (!hvalid) {
#pragma unroll
        for (int j = 0; j < 16; ++j) hv[j] = 0.f;
      }
      float acc[8] = {0,0,0,0,0,0,0,0};
#pragma unroll
      for (int cc = 0; cc < 16; ++cc) {
#pragma unroll
        for (int q = 0; q < 8; ++q) acc[q] = fmaf(w[q][cc], hv[cc], acc[q]);
      }
      float a4[4];
#pragma unroll
      for (int g = 0; g < 4; ++g) {
        float send = (lane & 1) ? acc[g] : acc[g + 4];
        float recv = __shfl_xor(send, 1, 64);
        a4[g] = ((lane & 1) ? acc[g + 4] : acc[g]) + recv;
      }
      float b2v[2];
#pragma unroll
      for (int j = 0; j < 2; ++j) {
        float send = (lane & 2) ? a4[j] : a4[j + 2];
        float recv = __shfl_xor(send, 2, 64);
        b2v[j] = ((lane & 2) ? a4[j + 2] : a4[j]) + recv;
      }
      float c1;
      {
        float send = (lane & 4) ? b2v[0] : b2v[1];
        float recv = __shfl_xor(send, 4, 64);
        c1 = ((lane & 4) ? b2v[1] : b2v[0]) + recv;
      }
      c1 += __shfl_xor(c1, 8, 64);
      c1 += __shfl_xor(c1, 16, 64);
      c1 += __shfl_xor(c1, 32, 64);
      float pre = c1 + bias_lane;
      float s2 = __shfl_xor(pre, 2, 64);
      float s4 = __shfl_xor(pre, 4, 64);
      float s6 = __shfl_xor(pre, 6, 64);
      float prei = sel4(G,     pre, s4, s2, s6);
      float pref = sel4(G ^ 1, pre, s4, s2, s6);
      float preg = sel4(G ^ 2, pre, s4, s2, s6);
      float preo = sel4(G ^ 3, pre, s4, s2, s6);
      float gi = sigm(prei), gf = sigm(pref), gg = tanh_f(preg), go = sigm(preo);
      c_reg = gf * c_reg + gi * gg;
      float hnew = go * tanh_f(c_reg);
      // fused output projection: out[t] += h_uB*Wo[uB] + h_{uB+1}*Wo[uB+1]
      float v = hnew * wout_lane;
      v += __shfl_xor(v, 1, 64);
      if (lane == 0) atomicAdd(d_out + t, (uB == 0) ? (v + b_out0) : v);
      if (lane < 2) {
        st2_sc(h2ring + (size_t)(t % RD) * 1024 + (uB + lane) * 2, hnew, (unsigned)(t + 1));
        if (t == T_LEN - 1) {
          d_out[T_LEN + HID + uB + lane] = hnew;          // hT1
          d_out[T_LEN + 3 * HID + uB + lane] = c_reg;     // cT1
        }
      }
    }
  }
}

extern "C" void kernel_launch(void* const* d_in, const int* in_sizes, int n_in,
                              void* d_out, int out_size, void* d_ws, size_t ws_size,
                              hipStream_t stream) {
  const float* in_states = (const float*)d_in[0];
  const float* W_in  = (const float*)d_in[1];
  const float* b_in  = (const float*)d_in[2];
  const float* W_ih0 = (const float*)d_in[3];
  const float* W_hh0 = (const float*)d_in[4];
  const float* b_ih0 = (const float*)d_in[5];
  const float* b_hh0 = (const float*)d_in[6];
  const float* W_ih1 = (const float*)d_in[7];
  const float* W_hh1 = (const float*)d_in[8];
  const float* b_ih1 = (const float*)d_in[9];
  const float* b_hh1 = (const float*)d_in[10];
  const float* W_out = (const float*)d_in[11];
  const float* b_out = (const float*)d_in[12];

  float* ws = (float*)d_ws;
  size_t o = 0;
  float* W_comb = ws + o;    o += (size_t)G4H * NIN;       // 81920
  float* bias_comb = ws + o; o += G4H;                     // 2048
  float* h1pair = ws + o;    o += (size_t)T_LEN * HID * 2; // 32 MB (pairs)
  float* h2ring = ws + o;    o += (size_t)RD * HID * 2;    // 32 KB (ring)
  // total ~34 MB of d_ws; seq words validate against 0xAA poison (no memset)

  // outputs region accumulated via atomicAdd -> must start at 0
  hipMemsetAsync(d_out, 0, (size_t)T_LEN * sizeof(float), stream);

  prep_kernel<<<G4H, 64, 0, stream>>>(W_in, b_in, W_ih0, b_ih0, b_hh0,
                                      W_comb, bias_comb);
  scan_kernel<<<512, 64, 0, stream>>>(in_states, W_hh0, W_ih1, W_hh1,
                                      b_ih1, b_hh1, W_comb, bias_comb,
                                      W_out, b_out,
                                      h1pair, h2ring, (float*)d_out);
}

// Round 6
// 46178.909 us; speedup vs baseline: 1.0467x; 1.0467x over previous
//
#include <hip/hip_runtime.h>

#define T_LEN 8192
#define NIN   40
#define E_DIM 256
#define HID   512
#define G4H   2048
#define RD    16    // h2 ring depth (L1 waves provably within 1 step of each other)

// ---------- MALL-coherent (cross-XCD) access, inline asm ----------
__device__ __forceinline__ float4 ld4_sc(const float* p) {
  float4 v;
  asm volatile("global_load_dwordx4 %0, %1, off sc0 sc1" : "=v"(v) : "v"(p));
  return v;  // NOT valid until s_waitcnt vmcnt(0)
}
__device__ __forceinline__ void st2_sc(float* p, float h, unsigned seq) {
  union { float2 f; uint2 u; } pv;
  pv.u.x = __float_as_uint(h); pv.u.y = seq;
  asm volatile("global_store_dwordx2 %0, %1, off sc0 sc1" :: "v"(p), "v"(pv.f) : "memory");
}
#define VM_FENCE() do { asm volatile("s_waitcnt vmcnt(0)" ::: "memory"); \
                        __builtin_amdgcn_sched_barrier(0); } while (0)

__device__ __forceinline__ float sigm(float x) {
  x = fminf(20.f, fmaxf(-20.f, x));
  float e = __builtin_amdgcn_exp2f(-1.442695040888963f * x);
  return __builtin_amdgcn_rcpf(1.f + e);
}
__device__ __forceinline__ float tanh_f(float x) {
  x = fminf(10.f, fmaxf(-10.f, x));
  float e = __builtin_amdgcn_exp2f(-2.885390081777927f * x);  // e^(-2x)
  return (1.f - e) * __builtin_amdgcn_rcpf(1.f + e);
}
__device__ __forceinline__ float sel4(int k, float a0, float a1, float a2, float a3) {
  float r = a0;
  r = (k == 1) ? a1 : r;
  r = (k == 2) ? a2 : r;
  r = (k == 3) ? a3 : r;
  return r;
}

// ---------------- phase 0: W_comb = W_ih0 @ W_in  [2048 x 40], bias_comb ----
__global__ __launch_bounds__(64) void prep_kernel(
    const float* __restrict__ W_in, const float* __restrict__ b_in,
    const float* __restrict__ W_ih0, const float* __restrict__ b_ih0,
    const float* __restrict__ b_hh0,
    float* __restrict__ W_comb, float* __restrict__ bias_comb)
{
  const int r = blockIdx.x;        // 0..2047
  const int lane = threadIdx.x;    // 0..63
  float bp = 0.f;
  for (int e = lane; e < E_DIM; e += 64) bp += W_ih0[(size_t)r * E_DIM + e] * b_in[e];
  float acc = 0.f;
  if (lane < NIN) {
    for (int e = 0; e < E_DIM; ++e)
      acc += W_ih0[(size_t)r * E_DIM + e] * W_in[(size_t)e * NIN + lane];
  }
#pragma unroll
  for (int m = 1; m < 64; m <<= 1) bp += __shfl_xor(bp, m, 64);
  if (lane < NIN) W_comb[(size_t)r * NIN + lane] = acc;
  if (lane == 0) bias_comb[r] = bp + b_ih0[r] + b_hh0[r];
}

// ---------------- phase 1: barrier-free pipelined 2-layer scan ----------------
// 512 blocks x 64 threads (one wave each, fully independent; no __syncthreads,
// no flags). h exchanged as {f32,seq} 8B atomic pairs via device-scope (MALL)
// loads/stores; consumers poll the data itself with s_sleep backoff.
// blocks 0..255: layer0 unit pair bid*2. blocks 256..511: layer1 unit pair.
// Output projection: per-wave partials to outpart[t*256+wg]; reduced later.
__global__ __launch_bounds__(64, 1) void scan_kernel(
    const float* __restrict__ in_states,
    const float* __restrict__ W_hh0,
    const float* __restrict__ W_ih1,
    const float* __restrict__ W_hh1,
    const float* __restrict__ b_ih1,
    const float* __restrict__ b_hh1,
    const float* __restrict__ W_comb,
    const float* __restrict__ bias_comb,
    const float* __restrict__ W_out,
    float* __restrict__ h1pair,   // [T][512] pairs (full history)
    float* __restrict__ h2ring,   // [RD][512] pairs (ring)
    float* __restrict__ outpart,  // [T][256] partial output dots
    float* __restrict__ d_out)
{
  const int lane = threadIdx.x;      // 0..63
  const int bid  = blockIdx.x;
  const int G    = (lane & 2) | ((lane >> 2) & 1);   // gate id after collapse

  if (bid < 256) {
    // ======================= layer 0 (units uA, uA+1) =======================
    const int uA = bid * 2;
    float w[8][8];                   // W_hh0 rows q: gate=q&3, unit=q>>2
#pragma unroll
    for (int q = 0; q < 8; ++q) {
      int R = (q & 3) * HID + uA + (q >> 2);
      const float4* p = (const float4*)(W_hh0 + (size_t)R * HID + lane * 8);
      float4 a = p[0], b = p[1];
      w[q][0]=a.x; w[q][1]=a.y; w[q][2]=a.z; w[q][3]=a.w;
      w[q][4]=b.x; w[q][5]=b.y; w[q][6]=b.z; w[q][7]=b.w;
    }
    float w2[8];                     // W_comb col `lane` for the 8 rows
#pragma unroll
    for (int q = 0; q < 8; ++q) {
      int R = (q & 3) * HID + uA + (q >> 2);
      w2[q] = (lane < NIN) ? W_comb[(size_t)R * NIN + lane] : 0.f;
    }
    const float bias_lane = bias_comb[G * HID + uA + (lane & 1)];
    float in_cur = (lane < NIN) ? in_states[lane] : 0.f;
    float c_reg = 0.f;

    for (int t = 0; t < T_LEN; ++t) {
      float in_nxt = (lane < NIN && t + 1 < T_LEN)
                   ? in_states[(size_t)(t + 1) * NIN + lane] : 0.f;
      float hv[8];
      if (t > 0) {
        const float* hp = h1pair + ((size_t)(t - 1) << 10) + lane * 16;
        const unsigned e = (unsigned)t;  // stored seq = (t-1)+1
        float4 A, B, C, D; int spin = 0;
        for (;;) {
          A = ld4_sc(hp); B = ld4_sc(hp + 4); C = ld4_sc(hp + 8); D = ld4_sc(hp + 12);
          VM_FENCE();
          unsigned bad = (__float_as_uint(A.y) ^ e) | (__float_as_uint(A.w) ^ e)
                       | (__float_as_uint(B.y) ^ e) | (__float_as_uint(B.w) ^ e)
                       | (__float_as_uint(C.y) ^ e) | (__float_as_uint(C.w) ^ e)
                       | (__float_as_uint(D.y) ^ e) | (__float_as_uint(D.w) ^ e);
          if (__all(bad == 0u)) break;
          if (++spin > 2) asm volatile("s_sleep 1");
        }
        hv[0]=A.x; hv[1]=A.z; hv[2]=B.x; hv[3]=B.z;
        hv[4]=C.x; hv[5]=C.z; hv[6]=D.x; hv[7]=D.z;
      } else {
#pragma unroll
        for (int j = 0; j < 8; ++j) hv[j] = 0.f;
      }
      float acc[8];
#pragma unroll
      for (int q = 0; q < 8; ++q) acc[q] = w2[q] * in_cur;   // input-dot share
#pragma unroll
      for (int cc = 0; cc < 8; ++cc) {
#pragma unroll
        for (int q = 0; q < 8; ++q) acc[q] = fmaf(w[q][cc], hv[cc], acc[q]);
      }
      // collapsing butterfly: 8 accs / 64 lanes -> 1 value per lane
      float a4[4];
#pragma unroll
      for (int g = 0; g < 4; ++g) {
        float send = (lane & 1) ? acc[g] : acc[g + 4];
        float recv = __shfl_xor(send, 1, 64);
        a4[g] = ((lane & 1) ? acc[g + 4] : acc[g]) + recv;
      }
      float b2[2];
#pragma unroll
      for (int j = 0; j < 2; ++j) {
        float send = (lane & 2) ? a4[j] : a4[j + 2];
        float recv = __shfl_xor(send, 2, 64);
        b2[j] = ((lane & 2) ? a4[j + 2] : a4[j]) + recv;
      }
      float c1;
      {
        float send = (lane & 4) ? b2[0] : b2[1];
        float recv = __shfl_xor(send, 4, 64);
        c1 = ((lane & 4) ? b2[1] : b2[0]) + recv;
      }
      c1 += __shfl_xor(c1, 8, 64);
      c1 += __shfl_xor(c1, 16, 64);
      c1 += __shfl_xor(c1, 32, 64);
      float pre = c1 + bias_lane;    // lane holds (unit uA+(lane&1), gate G)
      float s2 = __shfl_xor(pre, 2, 64);   // gate G^2
      float s4 = __shfl_xor(pre, 4, 64);   // gate G^1
      float s6 = __shfl_xor(pre, 6, 64);   // gate G^3
      float prei = sel4(G,     pre, s4, s2, s6);
      float pref = sel4(G ^ 1, pre, s4, s2, s6);
      float preg = sel4(G ^ 2, pre, s4, s2, s6);
      float preo = sel4(G ^ 3, pre, s4, s2, s6);
      float gi = sigm(prei), gf = sigm(pref), gg = tanh_f(preg), go = sigm(preo);
      c_reg = gf * c_reg + gi * gg;
      float hnew = go * tanh_f(c_reg);
      if (lane < 2) {
        st2_sc(h1pair + ((size_t)t << 10) + (uA + lane) * 2, hnew, (unsigned)(t + 1));
        if (t == T_LEN - 1) {
          d_out[T_LEN + uA + lane] = hnew;              // hT0
          d_out[T_LEN + 2 * HID + uA + lane] = c_reg;   // cT0
        }
      }
      in_cur = in_nxt;
    }
  } else {
    // ======================= layer 1 (units uB, uB+1) =======================
    const int wg = bid - 256;
    const int uB = wg * 2;
    const float* Wsrc = (lane < 32) ? W_ih1 : W_hh1;
    const int c0 = (lane & 31) * 16;
    float w[8][16];
#pragma unroll
    for (int q = 0; q < 8; ++q) {
      int R = (q & 3) * HID + uB + (q >> 2);
      const float4* p = (const float4*)(Wsrc + (size_t)R * HID + c0);
      float4 x0 = p[0], x1 = p[1], x2 = p[2], x3 = p[3];
      w[q][0]=x0.x;  w[q][1]=x0.y;  w[q][2]=x0.z;  w[q][3]=x0.w;
      w[q][4]=x1.x;  w[q][5]=x1.y;  w[q][6]=x1.z;  w[q][7]=x1.w;
      w[q][8]=x2.x;  w[q][9]=x2.y;  w[q][10]=x2.z; w[q][11]=x2.w;
      w[q][12]=x3.x; w[q][13]=x3.y; w[q][14]=x3.z; w[q][15]=x3.w;
    }
    const int brow = G * HID + uB + (lane & 1);
    const float bias_lane = b_ih1[brow] + b_hh1[brow];
    const float wout_lane = W_out[uB + (lane & 1)];
    float c_reg = 0.f;

    for (int t = 0; t < T_LEN; ++t) {
      const bool is_h1 = (lane < 32);
      const bool hvalid = is_h1 || (t > 0);
      const int rslot = (t > 0) ? ((t - 1) % RD) : 0;
      const float* hp = is_h1
          ? (h1pair + ((size_t)t << 10) + lane * 32)
          : (h2ring + (size_t)rslot * 1024 + (lane - 32) * 32);
      const unsigned e = is_h1 ? (unsigned)(t + 1) : (unsigned)t;
      float4 P0, P1, P2, P3, P4, P5, P6, P7; int spin = 0;
      for (;;) {
        P0 = ld4_sc(hp);      P1 = ld4_sc(hp + 4);
        P2 = ld4_sc(hp + 8);  P3 = ld4_sc(hp + 12);
        P4 = ld4_sc(hp + 16); P5 = ld4_sc(hp + 20);
        P6 = ld4_sc(hp + 24); P7 = ld4_sc(hp + 28);
        VM_FENCE();
        unsigned bad = (__float_as_uint(P0.y) ^ e) | (__float_as_uint(P0.w) ^ e)
                     | (__float_as_uint(P1.y) ^ e) | (__float_as_uint(P1.w) ^ e)
                     | (__float_as_uint(P2.y) ^ e) | (__float_as_uint(P2.w) ^ e)
                     | (__float_as_uint(P3.y) ^ e) | (__float_as_uint(P3.w) ^ e)
                     | (__float_as_uint(P4.y) ^ e) | (__float_as_uint(P4.w) ^ e)
                     | (__float_as_uint(P5.y) ^ e) | (__float_as_uint(P5.w) ^ e)
                     | (__float_as_uint(P6.y) ^ e) | (__float_as_uint(P6.w) ^ e)
                     | (__float_as_uint(P7.y) ^ e) | (__float_as_uint(P7.w) ^ e);
        if (__all((bad == 0u) || !hvalid)) break;
        if (++spin > 2) asm volatile("s_sleep 1");
      }
      float hv[16];
      hv[0]=P0.x;  hv[1]=P0.z;  hv[2]=P1.x;  hv[3]=P1.z;
      hv[4]=P2.x;  hv[5]=P2.z;  hv[6]=P3.x;  hv[7]=P3.z;
      hv[8]=P4.x;  hv[9]=P4.z;  hv[10]=P5.x; hv[11]=P5.z;
      hv[12]=P6.x; hv[13]=P6.z; hv[14]=P7.x; hv[15]=P7.z;
      if (!hvalid) {
#pragma unroll
        for (int j = 0; j < 16; ++j) hv[j] = 0.f;
      }
      float acc[8] = {0,0,0,0,0,0,0,0};
#pragma unroll
      for (int cc = 0; cc < 16; ++cc) {
#pragma unroll
        for (int q = 0; q < 8; ++q) acc[q] = fmaf(w[q][cc], hv[cc], acc[q]);
      }
      float a4[4];
#pragma unroll
      for (int g = 0; g < 4; ++g) {
        float send = (lane & 1) ? acc[g] : acc[g + 4];
        float recv = __shfl_xor(send, 1, 64);
        a4[g] = ((lane & 1) ? acc[g + 4] : acc[g]) + recv;
      }
      float b2v[2];
#pragma unroll
      for (int j = 0; j < 2; ++j) {
        float send = (lane & 2) ? a4[j] : a4[j + 2];
        float recv = __shfl_xor(send, 2, 64);
        b2v[j] = ((lane & 2) ? a4[j + 2] : a4[j]) + recv;
      }
      float c1;
      {
        float send = (lane & 4) ? b2v[0] : b2v[1];
        float recv = __shfl_xor(send, 4, 64);
        c1 = ((lane & 4) ? b2v[1] : b2v[0]) + recv;
      }
      c1 += __shfl_xor(c1, 8, 64);
      c1 += __shfl_xor(c1, 16, 64);
      c1 += __shfl_xor(c1, 32, 64);
      float pre = c1 + bias_lane;
      float s2 = __shfl_xor(pre, 2, 64);
      float s4 = __shfl_xor(pre, 4, 64);
      float s6 = __shfl_xor(pre, 6, 64);
      float prei = sel4(G,     pre, s4, s2, s6);
      float pref = sel4(G ^ 1, pre, s4, s2, s6);
      float preg = sel4(G ^ 2, pre, s4, s2, s6);
      float preo = sel4(G ^ 3, pre, s4, s2, s6);
      float gi = sigm(prei), gf = sigm(pref), gg = tanh_f(preg), go = sigm(preo);
      c_reg = gf * c_reg + gi * gg;
      float hnew = go * tanh_f(c_reg);
      // output-projection partial for this wave's 2 units (plain store,
      // reduced by out_kernel -- NO same-address atomics)
      float v = hnew * wout_lane;
      v += __shfl_xor(v, 1, 64);
      if (lane == 0) outpart[(size_t)t * 256 + wg] = v;
      if (lane < 2) {
        st2_sc(h2ring + (size_t)(t % RD) * 1024 + (uB + lane) * 2, hnew, (unsigned)(t + 1));
        if (t == T_LEN - 1) {
          d_out[T_LEN + HID + uB + lane] = hnew;          // hT1
          d_out[T_LEN + 3 * HID + uB + lane] = c_reg;     // cT1
        }
      }
    }
  }
}

// ---------------- phase 2: outputs[t] = sum(outpart[t][:]) + b_out ----------
__global__ __launch_bounds__(256) void out_kernel(
    const float* __restrict__ outpart, const float* __restrict__ b_out,
    float* __restrict__ d_out)
{
  int t = blockIdx.x * 4 + (threadIdx.x >> 6);
  int lane = threadIdx.x & 63;
  const float* pp = outpart + (size_t)t * 256 + lane;
  float s = pp[0] + pp[64] + pp[128] + pp[192];
#pragma unroll
  for (int m = 1; m < 64; m <<= 1) s += __shfl_xor(s, m, 64);
  if (lane == 0) d_out[t] = s + b_out[0];
}

extern "C" void kernel_launch(void* const* d_in, const int* in_sizes, int n_in,
                              void* d_out, int out_size, void* d_ws, size_t ws_size,
                              hipStream_t stream) {
  const float* in_states = (const float*)d_in[0];
  const float* W_in  = (const float*)d_in[1];
  const float* b_in  = (const float*)d_in[2];
  const float* W_ih0 = (const float*)d_in[3];
  const float* W_hh0 = (const float*)d_in[4];
  const float* b_ih0 = (const float*)d_in[5];
  const float* b_hh0 = (const float*)d_in[6];
  const float* W_ih1 = (const float*)d_in[7];
  const float* W_hh1 = (const float*)d_in[8];
  const float* b_ih1 = (const float*)d_in[9];
  const float* b_hh1 = (const float*)d_in[10];
  const float* W_out = (const float*)d_in[11];
  const float* b_out = (const float*)d_in[12];

  float* ws = (float*)d_ws;
  size_t o = 0;
  float* W_comb = ws + o;    o += (size_t)G4H * NIN;       // 81920
  float* bias_comb = ws + o; o += G4H;                     // 2048
  float* h1pair = ws + o;    o += (size_t)T_LEN * HID * 2; // 32 MB (pairs)
  float* h2ring = ws + o;    o += (size_t)RD * HID * 2;    // 64 KB (ring)
  float* outpart = ws + o;   o += (size_t)T_LEN * 256;     // 8 MB partials
  // total ~40.5 MB of d_ws; seq words self-validate vs 0xAA poison (no memset);
  // outpart is fully overwritten every launch before out_kernel reads it.

  prep_kernel<<<G4H, 64, 0, stream>>>(W_in, b_in, W_ih0, b_ih0, b_hh0,
                                      W_comb, bias_comb);
  scan_kernel<<<512, 64, 0, stream>>>(in_states, W_hh0, W_ih1, W_hh1,
                                      b_ih1, b_hh1, W_comb, bias_comb, W_out,
                                      h1pair, h2ring, outpart, (float*)d_out);
  out_kernel<<<2048, 256, 0, stream>>>(outpart, b_out, (float*)d_out);
}